// Round 2
// baseline (4858.407 us; speedup 1.0000x reference)
//
#include <hip/hip_runtime.h>

#define NB 32
#define NA 9
#define FH 100
#define FW 100
#define HWSZ (FH*FW)          // 10000
#define NANCH (HWSZ*NA)       // 90000
#define PRE 6000
#define POST 300
#define SORTN 8192
#define NWORD 188             // ceil(6000/32)
#define NEGV -1000000000.0f
#define NMS_T 0.7f

__device__ __forceinline__ unsigned int f2sort(float f) {
  unsigned int u = __float_as_uint(f);
  return (u & 0x80000000u) ? ~u : (u | 0x80000000u);
}

// Decode one anchor's clipped box. i in [0, NANCH): i = (h*FW + w)*NA + a
__device__ __forceinline__ float4 decode_box(const float* __restrict__ pred,
                                             const float* __restrict__ anchors,
                                             int b, int i, float imw, float imh) {
  int hw = i / NA; int a = i - hw * NA;
  int h = hw / FW; int w = hw - h * FW;
  float sx = (float)(w * 16);
  float sy = (float)(h * 16);
  float ax1 = anchors[a*4+0] + sx, ay1 = anchors[a*4+1] + sy;
  float ax2 = anchors[a*4+2] + sx, ay2 = anchors[a*4+3] + sy;
  float wa = ax2 - ax1 + 1.0f, ha = ay2 - ay1 + 1.0f;
  float cxa = ax1 + 0.5f*(wa - 1.0f), cya = ay1 + 0.5f*(ha - 1.0f);
  size_t base = (((size_t)b*36 + a*4)*FH + h)*FW + w;
  float dx = pred[base];
  float dy = pred[base + HWSZ];
  float dw = pred[base + 2*HWSZ];
  float dh = pred[base + 3*HWSZ];
  float cx = dx*wa + cxa, cy = dy*ha + cya;
  float pw = expf(dw)*wa, ph = expf(dh)*ha;
  float x1 = fminf(fmaxf(cx - 0.5f*(pw - 1.0f), 0.0f), imw - 1.0f);
  float y1 = fminf(fmaxf(cy - 0.5f*(ph - 1.0f), 0.0f), imh - 1.0f);
  float x2 = fminf(fmaxf(cx + 0.5f*(pw - 1.0f), 0.0f), imw - 1.0f);
  float y2 = fminf(fmaxf(cy + 0.5f*(ph - 1.0f), 0.0f), imh - 1.0f);
  return make_float4(x1, y1, x2, y2);
}

// K1: per-anchor score with min-size filter -> sortable key
__global__ void k_decode(const float* __restrict__ cls,
                         const float* __restrict__ pred,
                         const float* __restrict__ iminfo,
                         const float* __restrict__ anchors,
                         unsigned long long* __restrict__ keys) {
  int gid = blockIdx.x * blockDim.x + threadIdx.x;
  if (gid >= NB * NANCH) return;
  int b = gid / NANCH;
  int i = gid - b * NANCH;
  int hw = i / NA; int a = i - hw * NA;
  int h = hw / FW; int w = hw - h * FW;
  float score = cls[(((size_t)b*18 + 9 + a)*FH + h)*FW + w];
  float imh = iminfo[b*3+0], imw = iminfo[b*3+1], sc = iminfo[b*3+2];
  float4 bx = decode_box(pred, anchors, b, i, imw, imh);
  float msz = 16.0f * sc;
  bool keep = ((bx.z - bx.x + 1.0f) >= msz) && ((bx.w - bx.y + 1.0f) >= msz);
  float sf = keep ? score : NEGV;
  unsigned long long key = ((unsigned long long)f2sort(sf) << 32)
                         | (unsigned int)(~(unsigned int)i);
  keys[(size_t)b * NANCH + i] = key;
}

// K2: per-batch block: radix-threshold select -> compact -> bitonic sort ->
// decode top-6000 boxes + live mask to GLOBAL (NMS moved to k_nms)
#define SMEM_BYTES (65536 + 16384 + 16384 + 64)
__global__ __launch_bounds__(1024, 1) void k_select(
    const unsigned long long* __restrict__ keys,
    const float* __restrict__ pred,
    const float* __restrict__ iminfo,
    const float* __restrict__ anchors,
    float4* __restrict__ boxes_g,
    unsigned int* __restrict__ live_g) {
  __shared__ __align__(16) unsigned char smemRaw[SMEM_BYTES];
  unsigned long long* cand = (unsigned long long*)smemRaw;            // [8192] 65536B
  unsigned int* histA = (unsigned int*)(smemRaw + 65536);             // [4096]
  unsigned int* histB = (unsigned int*)(smemRaw + 81920);             // [4096]
  int* scal = (int*)(smemRaw + 98304);                                // [16]

  const int b = blockIdx.x;
  const int tid = threadIdx.x;
  const unsigned long long* kb = keys + (size_t)b * NANCH;

  // ---- level-1 histogram: sortable bits [31:20] ----
  for (int i = tid; i < 4096; i += 1024) histA[i] = 0;
  __syncthreads();
  for (int i = tid; i < NANCH; i += 1024)
    atomicAdd(&histA[(unsigned int)(kb[i] >> 52)], 1u);
  __syncthreads();
  {
    unsigned int *src = histA, *dst = histB;
    for (int d = 1; d < 4096; d <<= 1) {
      for (int i = tid; i < 4096; i += 1024) {
        unsigned int v = src[i];
        if (i + d < 4096) v += src[i + d];
        dst[i] = v;
      }
      __syncthreads();
      unsigned int* t = src; src = dst; dst = t;
    }
    for (int i = tid; i < 4096; i += 1024) {
      unsigned int s = src[i];
      unsigned int sn = (i < 4095) ? src[i + 1] : 0u;
      if (s >= PRE && sn < PRE) { scal[1] = i; scal[2] = (int)sn; }
    }
    __syncthreads();
  }
  const int cb = scal[1];
  const unsigned int nG = (unsigned int)scal[2];
  __syncthreads();

  // ---- level-2 histogram: within coarse bin, sortable bits [19:8] ----
  for (int i = tid; i < 4096; i += 1024) histA[i] = 0;
  __syncthreads();
  for (int i = tid; i < NANCH; i += 1024) {
    unsigned long long k = kb[i];
    if ((int)(k >> 52) == cb)
      atomicAdd(&histA[(unsigned int)((k >> 40) & 0xFFFull)], 1u);
  }
  __syncthreads();
  {
    unsigned int *src = histA, *dst = histB;
    for (int d = 1; d < 4096; d <<= 1) {
      for (int i = tid; i < 4096; i += 1024) {
        unsigned int v = src[i];
        if (i + d < 4096) v += src[i + d];
        dst[i] = v;
      }
      __syncthreads();
      unsigned int* t = src; src = dst; dst = t;
    }
    unsigned int need2 = PRE - nG;
    for (int i = tid; i < 4096; i += 1024) {
      unsigned int s = src[i];
      unsigned int sn = (i < 4095) ? src[i + 1] : 0u;
      if (s >= need2 && sn < need2) scal[3] = i;
    }
    __syncthreads();
  }
  const unsigned int thrT = ((unsigned int)cb << 20) | ((unsigned int)scal[3] << 8);

  // ---- compaction of keys with sortable >= thrT ----
  if (tid == 0) scal[0] = 0;
  __syncthreads();
  for (int i = tid; i < NANCH; i += 1024) {
    unsigned long long k = kb[i];
    if ((unsigned int)(k >> 32) >= thrT) {
      int p = atomicAdd(&scal[0], 1);
      if (p < SORTN) cand[p] = k;
    }
  }
  __syncthreads();
  {
    int cnt = scal[0]; if (cnt > SORTN) cnt = SORTN;
    for (int i = tid; i < SORTN; i += 1024)
      if (i >= cnt) cand[i] = 0ull;
  }
  __syncthreads();

  // ---- bitonic sort, descending (ties: larger low-word = smaller index first) ----
  for (int k = 2; k <= SORTN; k <<= 1) {
    for (int j = k >> 1; j > 0; j >>= 1) {
      for (int i = tid; i < SORTN; i += 1024) {
        int ixj = i ^ j;
        if (ixj > i) {
          unsigned long long a0 = cand[i], a1 = cand[ixj];
          bool up = (i & k) != 0;
          bool sw = up ? (a0 > a1) : (a0 < a1);
          if (sw) { cand[i] = a1; cand[ixj] = a0; }
        }
      }
      __syncthreads();
    }
  }

  // ---- decode top-6000 boxes to global ----
  const float imh = iminfo[b*3+0], imw = iminfo[b*3+1];
  float4* bg = boxes_g + (size_t)b * PRE;
  for (int s = tid; s < PRE; s += 1024) {
    unsigned long long k = cand[s];
    unsigned int idx = ~(unsigned int)(k & 0xFFFFFFFFull);
    float4 bx = make_float4(0.f, 0.f, 0.f, 0.f);
    if (idx < NANCH) bx = decode_box(pred, anchors, b, (int)idx, imw, imh);
    bg[s] = bx;
  }
  // ---- live mask words to global: bit set iff s < PRE and score > NEG/2 ----
  const unsigned int liveThr = f2sort(-5.0e8f);
  for (int w = tid; w < NWORD; w += 1024) {
    unsigned int m = 0u;
    for (int k2 = 0; k2 < 32; ++k2) {
      int s = w * 32 + k2;
      if (s < PRE && (unsigned int)(cand[s] >> 32) > liveThr) m |= (1u << k2);
    }
    live_g[b * NWORD + w] = m;
  }
}

// K3: one wave per batch, barrier-free greedy NMS from LDS-resident boxes
__global__ __launch_bounds__(64, 1) void k_nms(
    const float4* __restrict__ boxes_g,
    const unsigned int* __restrict__ live_g,
    float* __restrict__ out) {
  __shared__ float4 bx[PRE];          // 96000B
  __shared__ unsigned int live[NWORD];
  __shared__ float4 obuf[POST];
  const int b = blockIdx.x;
  const int l = threadIdx.x;
  const float4* bg = boxes_g + (size_t)b * PRE;
  for (int i = l; i < PRE; i += 64) bx[i] = bg[i];
  for (int i = l; i < NWORD; i += 64) live[i] = live_g[b * NWORD + i];
  __syncthreads();

  int p = 0;
  int it = 0;
  for (; it < POST; ++it) {
    // ---- find first live index >= p (wave-parallel ballot scan) ----
    int j = -1;
    int bw = p >> 5;
    for (int r = bw; r < NWORD; r += 64) {
      int w = r + l;
      unsigned int m = (w < NWORD) ? live[w] : 0u;
      if (w == bw) m &= (0xFFFFFFFFu << (p & 31));
      unsigned long long bal = __ballot(m != 0u);
      if (bal) {
        int fl = __ffsll((unsigned long long)bal) - 1;
        unsigned int mm = __shfl(m, fl);
        j = ((r + fl) << 5) + __ffs(mm) - 1;
        break;
      }
    }
    if (j < 0) break;
    p = j + 1;
    float4 bj = bx[j];  // broadcast read
    if (l == 0) obuf[it] = bj;
    float areaJ = (bj.z - bj.x + 1.0f) * (bj.w - bj.y + 1.0f);
    // ---- suppress c in [p, PRE): ballot -> word updates by lanes 0/1 ----
    for (int c0 = p & ~63; c0 < PRE; c0 += 64) {
      int c = c0 + l;
      bool sup = false;
      if (c >= p) {
        float4 bk = bx[c];
        float xx1 = fmaxf(bj.x, bk.x);
        float yy1 = fmaxf(bj.y, bk.y);
        float xx2 = fminf(bj.z, bk.z);
        float yy2 = fminf(bj.w, bk.w);
        float inter = fmaxf(xx2 - xx1 + 1.0f, 0.0f) * fmaxf(yy2 - yy1 + 1.0f, 0.0f);
        float areaK = (bk.z - bk.x + 1.0f) * (bk.w - bk.y + 1.0f);
        float iou = inter / (areaJ + areaK - inter);
        sup = (iou > NMS_T);
      }
      unsigned long long bal = __ballot(sup);
      if (bal) {
        if (l == 0) live[(c0 >> 5)]     &= ~(unsigned int)(bal & 0xFFFFFFFFull);
        if (l == 1) live[(c0 >> 5) + 1] &= ~(unsigned int)(bal >> 32);
      }
    }
  }
  // ---- fill remaining (invalid) picks with zeros ----
  for (int k = it + l; k < POST; k += 64) obuf[k] = make_float4(0.f, 0.f, 0.f, 0.f);
  __syncthreads();
  // ---- coalesced output write: [b][POST][5] = (b, x1, y1, x2, y2) ----
  float* ob = out + (size_t)b * POST * 5;
  for (int i = l; i < POST * 5; i += 64) {
    int row = i / 5, col = i - row * 5;
    float v;
    if (col == 0) v = (float)b;
    else {
      float4 bb = obuf[row];
      v = (col == 1) ? bb.x : (col == 2) ? bb.y : (col == 3) ? bb.z : bb.w;
    }
    ob[i] = v;
  }
}

extern "C" void kernel_launch(void* const* d_in, const int* in_sizes, int n_in,
                              void* d_out, int out_size, void* d_ws, size_t ws_size,
                              hipStream_t stream) {
  const float* cls     = (const float*)d_in[0];
  const float* pred    = (const float*)d_in[1];
  const float* iminfo  = (const float*)d_in[2];
  const float* anchors = (const float*)d_in[3];
  float* out = (float*)d_out;

  unsigned char* ws = (unsigned char*)d_ws;
  unsigned long long* keys = (unsigned long long*)ws;                 // 23,040,000 B
  float4* boxes_g = (float4*)(ws + (size_t)NB * NANCH * 8);           //  3,072,000 B
  unsigned int* live_g = (unsigned int*)(ws + (size_t)NB * NANCH * 8
                                            + (size_t)NB * PRE * 16); //     24,064 B

  int total = NB * NANCH;
  int blocks = (total + 255) / 256;
  k_decode<<<blocks, 256, 0, stream>>>(cls, pred, iminfo, anchors, keys);
  k_select<<<NB, 1024, 0, stream>>>(keys, pred, iminfo, anchors, boxes_g, live_g);
  k_nms<<<NB, 64, 0, stream>>>(boxes_g, live_g, out);
}

// Round 3
// 1206.484 us; speedup vs baseline: 4.0269x; 4.0269x over previous
//
#include <hip/hip_runtime.h>

#define NB 32
#define NA 9
#define FH 100
#define FW 100
#define HWSZ (FH*FW)          // 10000
#define NANCH (HWSZ*NA)       // 90000
#define PRE 6000
#define POST 300
#define SORTN 8192
#define NWORD 188             // ceil(6000/32)
#define NEGV -1000000000.0f
#define NMS_T 0.7f
#define KPT 24                // boxes per thread in k_nms: 256*24 = 6144 >= 6000

__device__ __forceinline__ unsigned int f2sort(float f) {
  unsigned int u = __float_as_uint(f);
  return (u & 0x80000000u) ? ~u : (u | 0x80000000u);
}

// Decode one anchor's clipped box. i in [0, NANCH): i = (h*FW + w)*NA + a
__device__ __forceinline__ float4 decode_box(const float* __restrict__ pred,
                                             const float* __restrict__ anchors,
                                             int b, int i, float imw, float imh) {
  int hw = i / NA; int a = i - hw * NA;
  int h = hw / FW; int w = hw - h * FW;
  float sx = (float)(w * 16);
  float sy = (float)(h * 16);
  float ax1 = anchors[a*4+0] + sx, ay1 = anchors[a*4+1] + sy;
  float ax2 = anchors[a*4+2] + sx, ay2 = anchors[a*4+3] + sy;
  float wa = ax2 - ax1 + 1.0f, ha = ay2 - ay1 + 1.0f;
  float cxa = ax1 + 0.5f*(wa - 1.0f), cya = ay1 + 0.5f*(ha - 1.0f);
  size_t base = (((size_t)b*36 + a*4)*FH + h)*FW + w;
  float dx = pred[base];
  float dy = pred[base + HWSZ];
  float dw = pred[base + 2*HWSZ];
  float dh = pred[base + 3*HWSZ];
  float cx = dx*wa + cxa, cy = dy*ha + cya;
  float pw = expf(dw)*wa, ph = expf(dh)*ha;
  float x1 = fminf(fmaxf(cx - 0.5f*(pw - 1.0f), 0.0f), imw - 1.0f);
  float y1 = fminf(fmaxf(cy - 0.5f*(ph - 1.0f), 0.0f), imh - 1.0f);
  float x2 = fminf(fmaxf(cx + 0.5f*(pw - 1.0f), 0.0f), imw - 1.0f);
  float y2 = fminf(fmaxf(cy + 0.5f*(ph - 1.0f), 0.0f), imh - 1.0f);
  return make_float4(x1, y1, x2, y2);
}

// K1: per-anchor score with min-size filter -> sortable key
__global__ void k_decode(const float* __restrict__ cls,
                         const float* __restrict__ pred,
                         const float* __restrict__ iminfo,
                         const float* __restrict__ anchors,
                         unsigned long long* __restrict__ keys) {
  int gid = blockIdx.x * blockDim.x + threadIdx.x;
  if (gid >= NB * NANCH) return;
  int b = gid / NANCH;
  int i = gid - b * NANCH;
  int hw = i / NA; int a = i - hw * NA;
  int h = hw / FW; int w = hw - h * FW;
  float score = cls[(((size_t)b*18 + 9 + a)*FH + h)*FW + w];
  float imh = iminfo[b*3+0], imw = iminfo[b*3+1], sc = iminfo[b*3+2];
  float4 bx = decode_box(pred, anchors, b, i, imw, imh);
  float msz = 16.0f * sc;
  bool keep = ((bx.z - bx.x + 1.0f) >= msz) && ((bx.w - bx.y + 1.0f) >= msz);
  float sf = keep ? score : NEGV;
  unsigned long long key = ((unsigned long long)f2sort(sf) << 32)
                         | (unsigned int)(~(unsigned int)i);
  keys[(size_t)b * NANCH + i] = key;
}

// K2: per-batch block: radix-threshold select -> compact -> bitonic sort ->
// decode top-6000 boxes + live mask to GLOBAL
#define SMEM_BYTES (65536 + 16384 + 16384 + 64)
__global__ __launch_bounds__(1024, 1) void k_select(
    const unsigned long long* __restrict__ keys,
    const float* __restrict__ pred,
    const float* __restrict__ iminfo,
    const float* __restrict__ anchors,
    float4* __restrict__ boxes_g,
    unsigned int* __restrict__ live_g) {
  __shared__ __align__(16) unsigned char smemRaw[SMEM_BYTES];
  unsigned long long* cand = (unsigned long long*)smemRaw;            // [8192] 65536B
  unsigned int* histA = (unsigned int*)(smemRaw + 65536);             // [4096]
  unsigned int* histB = (unsigned int*)(smemRaw + 81920);             // [4096]
  int* scal = (int*)(smemRaw + 98304);                                // [16]

  const int b = blockIdx.x;
  const int tid = threadIdx.x;
  const unsigned long long* kb = keys + (size_t)b * NANCH;

  // ---- level-1 histogram: sortable bits [31:20] ----
  for (int i = tid; i < 4096; i += 1024) histA[i] = 0;
  __syncthreads();
  for (int i = tid; i < NANCH; i += 1024)
    atomicAdd(&histA[(unsigned int)(kb[i] >> 52)], 1u);
  __syncthreads();
  {
    unsigned int *src = histA, *dst = histB;
    for (int d = 1; d < 4096; d <<= 1) {
      for (int i = tid; i < 4096; i += 1024) {
        unsigned int v = src[i];
        if (i + d < 4096) v += src[i + d];
        dst[i] = v;
      }
      __syncthreads();
      unsigned int* t = src; src = dst; dst = t;
    }
    for (int i = tid; i < 4096; i += 1024) {
      unsigned int s = src[i];
      unsigned int sn = (i < 4095) ? src[i + 1] : 0u;
      if (s >= PRE && sn < PRE) { scal[1] = i; scal[2] = (int)sn; }
    }
    __syncthreads();
  }
  const int cb = scal[1];
  const unsigned int nG = (unsigned int)scal[2];
  __syncthreads();

  // ---- level-2 histogram: within coarse bin, sortable bits [19:8] ----
  for (int i = tid; i < 4096; i += 1024) histA[i] = 0;
  __syncthreads();
  for (int i = tid; i < NANCH; i += 1024) {
    unsigned long long k = kb[i];
    if ((int)(k >> 52) == cb)
      atomicAdd(&histA[(unsigned int)((k >> 40) & 0xFFFull)], 1u);
  }
  __syncthreads();
  {
    unsigned int *src = histA, *dst = histB;
    for (int d = 1; d < 4096; d <<= 1) {
      for (int i = tid; i < 4096; i += 1024) {
        unsigned int v = src[i];
        if (i + d < 4096) v += src[i + d];
        dst[i] = v;
      }
      __syncthreads();
      unsigned int* t = src; src = dst; dst = t;
    }
    unsigned int need2 = PRE - nG;
    for (int i = tid; i < 4096; i += 1024) {
      unsigned int s = src[i];
      unsigned int sn = (i < 4095) ? src[i + 1] : 0u;
      if (s >= need2 && sn < need2) scal[3] = i;
    }
    __syncthreads();
  }
  const unsigned int thrT = ((unsigned int)cb << 20) | ((unsigned int)scal[3] << 8);

  // ---- compaction of keys with sortable >= thrT ----
  if (tid == 0) scal[0] = 0;
  __syncthreads();
  for (int i = tid; i < NANCH; i += 1024) {
    unsigned long long k = kb[i];
    if ((unsigned int)(k >> 32) >= thrT) {
      int p = atomicAdd(&scal[0], 1);
      if (p < SORTN) cand[p] = k;
    }
  }
  __syncthreads();
  {
    int cnt = scal[0]; if (cnt > SORTN) cnt = SORTN;
    for (int i = tid; i < SORTN; i += 1024)
      if (i >= cnt) cand[i] = 0ull;
  }
  __syncthreads();

  // ---- bitonic sort, descending ----
  for (int k = 2; k <= SORTN; k <<= 1) {
    for (int j = k >> 1; j > 0; j >>= 1) {
      for (int i = tid; i < SORTN; i += 1024) {
        int ixj = i ^ j;
        if (ixj > i) {
          unsigned long long a0 = cand[i], a1 = cand[ixj];
          bool up = (i & k) != 0;
          bool sw = up ? (a0 > a1) : (a0 < a1);
          if (sw) { cand[i] = a1; cand[ixj] = a0; }
        }
      }
      __syncthreads();
    }
  }

  // ---- decode top-6000 boxes to global ----
  const float imh = iminfo[b*3+0], imw = iminfo[b*3+1];
  float4* bg = boxes_g + (size_t)b * PRE;
  for (int s = tid; s < PRE; s += 1024) {
    unsigned long long k = cand[s];
    unsigned int idx = ~(unsigned int)(k & 0xFFFFFFFFull);
    float4 bx = make_float4(0.f, 0.f, 0.f, 0.f);
    if (idx < NANCH) bx = decode_box(pred, anchors, b, (int)idx, imw, imh);
    bg[s] = bx;
  }
  // ---- live mask words to global ----
  const unsigned int liveThr = f2sort(-5.0e8f);
  for (int w = tid; w < NWORD; w += 1024) {
    unsigned int m = 0u;
    for (int k2 = 0; k2 < 32; ++k2) {
      int s = w * 32 + k2;
      if (s < PRE && (unsigned int)(cand[s] >> 32) > liveThr) m |= (1u << k2);
    }
    live_g[b * NWORD + w] = m;
  }
}

// K3: one 256-thread block per batch; register-resident boxes; ballot NMS
__global__ __launch_bounds__(256, 1) void k_nms(
    const float4* __restrict__ boxes_g,
    const unsigned int* __restrict__ live_g,
    float* __restrict__ out) {
  __shared__ float4 bxs[PRE];          // 96000B (for pick broadcast)
  __shared__ unsigned int live[NWORD];
  __shared__ float4 obuf[POST];
  __shared__ int scal[2];
  const int b = blockIdx.x;
  const int tid = threadIdx.x;
  const int wave = tid >> 6, lane = tid & 63;
  const float4* bg = boxes_g + (size_t)b * PRE;
  for (int i = tid; i < PRE; i += 256) bxs[i] = bg[i];
  for (int i = tid; i < NWORD; i += 256) live[i] = live_g[b * NWORD + i];
  __syncthreads();

  // register-resident boxes: thread owns c = k*256 + tid, k = 0..KPT-1
  float rx1[KPT], ry1[KPT], rx2[KPT], ry2[KPT];
  unsigned int alive = 0u;
  #pragma unroll
  for (int k = 0; k < KPT; ++k) {
    int c = k * 256 + tid;
    float4 bb = (c < PRE) ? bxs[c] : make_float4(0.f, 0.f, 0.f, 0.f);
    rx1[k] = bb.x; ry1[k] = bb.y; rx2[k] = bb.z; ry2[k] = bb.w;
    unsigned int lv = (c < PRE) ? ((live[c >> 5] >> (c & 31)) & 1u) : 0u;
    alive |= lv << k;
  }

  int p = 0, it = 0;
  for (; it < POST; ++it) {
    // ---- find first live index >= p: wave 0, ballot scan ----
    if (wave == 0) {
      int j = -1;
      int bw = p >> 5;
      for (int r = bw; r < NWORD; r += 64) {
        int w = r + lane;
        unsigned int m = (w < NWORD) ? live[w] : 0u;
        if (w == bw) m &= (0xFFFFFFFFu << (p & 31));
        unsigned long long bal = __ballot(m != 0u);
        if (bal) {
          int fl = __ffsll((unsigned long long)bal) - 1;
          unsigned int mm = __shfl(m, fl);
          j = ((r + fl) << 5) + __ffs(mm) - 1;
          break;
        }
      }
      if (lane == 0) scal[0] = j;
    }
    __syncthreads();
    int j = scal[0];
    if (j < 0) break;
    p = j + 1;
    float4 bj = bxs[j];  // LDS broadcast
    float areaJ = (bj.z - bj.x + 1.0f) * (bj.w - bj.y + 1.0f);
    if (tid == 0) obuf[it] = bj;
    // ---- suppression sweep over register boxes ----
    #pragma unroll
    for (int k = 0; k < KPT; ++k) {
      unsigned int ak = (alive >> k) & 1u;
      unsigned long long balA = __ballot(ak != 0u);
      if (!balA) continue;  // whole 64-box chunk dead (wave-uniform)
      bool sup = false;
      if (ak) {
        float xx1 = fmaxf(bj.x, rx1[k]);
        float yy1 = fmaxf(bj.y, ry1[k]);
        float xx2 = fminf(bj.z, rx2[k]);
        float yy2 = fminf(bj.w, ry2[k]);
        float inter = fmaxf(xx2 - xx1 + 1.0f, 0.0f) * fmaxf(yy2 - yy1 + 1.0f, 0.0f);
        float areaK = (rx2[k] - rx1[k] + 1.0f) * (ry2[k] - ry1[k] + 1.0f);
        float iou = inter / (areaJ + areaK - inter);
        sup = (iou > NMS_T);
      }
      unsigned long long bal = __ballot(sup);
      if (sup) alive &= ~(1u << k);
      if (bal) {
        int w0 = k * 8 + wave * 2;
        if (lane == 0) live[w0]     &= ~(unsigned int)(bal & 0xFFFFFFFFull);
        if (lane == 1) live[w0 + 1] &= ~(unsigned int)(bal >> 32);
      }
    }
    __syncthreads();
  }
  // ---- fill remaining picks with zeros ----
  for (int k = it + tid; k < POST; k += 256) obuf[k] = make_float4(0.f, 0.f, 0.f, 0.f);
  __syncthreads();
  // ---- coalesced output write: [b][POST][5] = (b, x1, y1, x2, y2) ----
  float* ob = out + (size_t)b * POST * 5;
  for (int i = tid; i < POST * 5; i += 256) {
    int row = i / 5, col = i - row * 5;
    float v;
    if (col == 0) v = (float)b;
    else {
      float4 bb = obuf[row];
      v = (col == 1) ? bb.x : (col == 2) ? bb.y : (col == 3) ? bb.z : bb.w;
    }
    ob[i] = v;
  }
}

extern "C" void kernel_launch(void* const* d_in, const int* in_sizes, int n_in,
                              void* d_out, int out_size, void* d_ws, size_t ws_size,
                              hipStream_t stream) {
  const float* cls     = (const float*)d_in[0];
  const float* pred    = (const float*)d_in[1];
  const float* iminfo  = (const float*)d_in[2];
  const float* anchors = (const float*)d_in[3];
  float* out = (float*)d_out;

  unsigned char* ws = (unsigned char*)d_ws;
  unsigned long long* keys = (unsigned long long*)ws;                 // 23,040,000 B
  float4* boxes_g = (float4*)(ws + (size_t)NB * NANCH * 8);           //  3,072,000 B
  unsigned int* live_g = (unsigned int*)(ws + (size_t)NB * NANCH * 8
                                            + (size_t)NB * PRE * 16); //     24,064 B

  int total = NB * NANCH;
  int blocks = (total + 255) / 256;
  k_decode<<<blocks, 256, 0, stream>>>(cls, pred, iminfo, anchors, keys);
  k_select<<<NB, 1024, 0, stream>>>(keys, pred, iminfo, anchors, boxes_g, live_g);
  k_nms<<<NB, 256, 0, stream>>>(boxes_g, live_g, out);
}

// Round 4
// 688.576 us; speedup vs baseline: 7.0557x; 1.7521x over previous
//
#include <hip/hip_runtime.h>

#define NB 32
#define NA 9
#define FH 100
#define FW 100
#define HWSZ (FH*FW)          // 10000
#define NANCH (HWSZ*NA)       // 90000
#define PRE 6000
#define POST 300
#define SORTN 8192
#define NWORD 188             // ceil(6000/32)
#define NEGV -1000000000.0f
#define NMS_T 0.7f
#define NT 512                // k_nms threads
#define KPT 12                // boxes per thread: 512*12 = 6144 >= 6000
#define BIGI 0x7FFFFFFF

__device__ __forceinline__ unsigned int f2sort(float f) {
  unsigned int u = __float_as_uint(f);
  return (u & 0x80000000u) ? ~u : (u | 0x80000000u);
}

// Decode one anchor's clipped box. i in [0, NANCH): i = (h*FW + w)*NA + a
__device__ __forceinline__ float4 decode_box(const float* __restrict__ pred,
                                             const float* __restrict__ anchors,
                                             int b, int i, float imw, float imh) {
  int hw = i / NA; int a = i - hw * NA;
  int h = hw / FW; int w = hw - h * FW;
  float sx = (float)(w * 16);
  float sy = (float)(h * 16);
  float ax1 = anchors[a*4+0] + sx, ay1 = anchors[a*4+1] + sy;
  float ax2 = anchors[a*4+2] + sx, ay2 = anchors[a*4+3] + sy;
  float wa = ax2 - ax1 + 1.0f, ha = ay2 - ay1 + 1.0f;
  float cxa = ax1 + 0.5f*(wa - 1.0f), cya = ay1 + 0.5f*(ha - 1.0f);
  size_t base = (((size_t)b*36 + a*4)*FH + h)*FW + w;
  float dx = pred[base];
  float dy = pred[base + HWSZ];
  float dw = pred[base + 2*HWSZ];
  float dh = pred[base + 3*HWSZ];
  float cx = dx*wa + cxa, cy = dy*ha + cya;
  float pw = expf(dw)*wa, ph = expf(dh)*ha;
  float x1 = fminf(fmaxf(cx - 0.5f*(pw - 1.0f), 0.0f), imw - 1.0f);
  float y1 = fminf(fmaxf(cy - 0.5f*(ph - 1.0f), 0.0f), imh - 1.0f);
  float x2 = fminf(fmaxf(cx + 0.5f*(pw - 1.0f), 0.0f), imw - 1.0f);
  float y2 = fminf(fmaxf(cy + 0.5f*(ph - 1.0f), 0.0f), imh - 1.0f);
  return make_float4(x1, y1, x2, y2);
}

// K1: per-anchor score with min-size filter -> sortable key
__global__ void k_decode(const float* __restrict__ cls,
                         const float* __restrict__ pred,
                         const float* __restrict__ iminfo,
                         const float* __restrict__ anchors,
                         unsigned long long* __restrict__ keys) {
  int gid = blockIdx.x * blockDim.x + threadIdx.x;
  if (gid >= NB * NANCH) return;
  int b = gid / NANCH;
  int i = gid - b * NANCH;
  int hw = i / NA; int a = i - hw * NA;
  int h = hw / FW; int w = hw - h * FW;
  float score = cls[(((size_t)b*18 + 9 + a)*FH + h)*FW + w];
  float imh = iminfo[b*3+0], imw = iminfo[b*3+1], sc = iminfo[b*3+2];
  float4 bx = decode_box(pred, anchors, b, i, imw, imh);
  float msz = 16.0f * sc;
  bool keep = ((bx.z - bx.x + 1.0f) >= msz) && ((bx.w - bx.y + 1.0f) >= msz);
  float sf = keep ? score : NEGV;
  unsigned long long key = ((unsigned long long)f2sort(sf) << 32)
                         | (unsigned int)(~(unsigned int)i);
  keys[(size_t)b * NANCH + i] = key;
}

// K2: per-batch block: radix-threshold select -> compact -> bitonic sort ->
// decode top-6000 boxes + live mask to GLOBAL
#define SMEM_BYTES (65536 + 16384 + 16384 + 64)
__global__ __launch_bounds__(1024, 1) void k_select(
    const unsigned long long* __restrict__ keys,
    const float* __restrict__ pred,
    const float* __restrict__ iminfo,
    const float* __restrict__ anchors,
    float4* __restrict__ boxes_g,
    unsigned int* __restrict__ live_g) {
  __shared__ __align__(16) unsigned char smemRaw[SMEM_BYTES];
  unsigned long long* cand = (unsigned long long*)smemRaw;            // [8192] 65536B
  unsigned int* histA = (unsigned int*)(smemRaw + 65536);             // [4096]
  unsigned int* histB = (unsigned int*)(smemRaw + 81920);             // [4096]
  int* scal = (int*)(smemRaw + 98304);                                // [16]

  const int b = blockIdx.x;
  const int tid = threadIdx.x;
  const unsigned long long* kb = keys + (size_t)b * NANCH;

  // ---- level-1 histogram: sortable bits [31:20] ----
  for (int i = tid; i < 4096; i += 1024) histA[i] = 0;
  __syncthreads();
  for (int i = tid; i < NANCH; i += 1024)
    atomicAdd(&histA[(unsigned int)(kb[i] >> 52)], 1u);
  __syncthreads();
  {
    unsigned int *src = histA, *dst = histB;
    for (int d = 1; d < 4096; d <<= 1) {
      for (int i = tid; i < 4096; i += 1024) {
        unsigned int v = src[i];
        if (i + d < 4096) v += src[i + d];
        dst[i] = v;
      }
      __syncthreads();
      unsigned int* t = src; src = dst; dst = t;
    }
    for (int i = tid; i < 4096; i += 1024) {
      unsigned int s = src[i];
      unsigned int sn = (i < 4095) ? src[i + 1] : 0u;
      if (s >= PRE && sn < PRE) { scal[1] = i; scal[2] = (int)sn; }
    }
    __syncthreads();
  }
  const int cb = scal[1];
  const unsigned int nG = (unsigned int)scal[2];
  __syncthreads();

  // ---- level-2 histogram: within coarse bin, sortable bits [19:8] ----
  for (int i = tid; i < 4096; i += 1024) histA[i] = 0;
  __syncthreads();
  for (int i = tid; i < NANCH; i += 1024) {
    unsigned long long k = kb[i];
    if ((int)(k >> 52) == cb)
      atomicAdd(&histA[(unsigned int)((k >> 40) & 0xFFFull)], 1u);
  }
  __syncthreads();
  {
    unsigned int *src = histA, *dst = histB;
    for (int d = 1; d < 4096; d <<= 1) {
      for (int i = tid; i < 4096; i += 1024) {
        unsigned int v = src[i];
        if (i + d < 4096) v += src[i + d];
        dst[i] = v;
      }
      __syncthreads();
      unsigned int* t = src; src = dst; dst = t;
    }
    unsigned int need2 = PRE - nG;
    for (int i = tid; i < 4096; i += 1024) {
      unsigned int s = src[i];
      unsigned int sn = (i < 4095) ? src[i + 1] : 0u;
      if (s >= need2 && sn < need2) scal[3] = i;
    }
    __syncthreads();
  }
  const unsigned int thrT = ((unsigned int)cb << 20) | ((unsigned int)scal[3] << 8);

  // ---- compaction of keys with sortable >= thrT ----
  if (tid == 0) scal[0] = 0;
  __syncthreads();
  for (int i = tid; i < NANCH; i += 1024) {
    unsigned long long k = kb[i];
    if ((unsigned int)(k >> 32) >= thrT) {
      int p = atomicAdd(&scal[0], 1);
      if (p < SORTN) cand[p] = k;
    }
  }
  __syncthreads();
  {
    int cnt = scal[0]; if (cnt > SORTN) cnt = SORTN;
    for (int i = tid; i < SORTN; i += 1024)
      if (i >= cnt) cand[i] = 0ull;
  }
  __syncthreads();

  // ---- bitonic sort, descending ----
  for (int k = 2; k <= SORTN; k <<= 1) {
    for (int j = k >> 1; j > 0; j >>= 1) {
      for (int i = tid; i < SORTN; i += 1024) {
        int ixj = i ^ j;
        if (ixj > i) {
          unsigned long long a0 = cand[i], a1 = cand[ixj];
          bool up = (i & k) != 0;
          bool sw = up ? (a0 > a1) : (a0 < a1);
          if (sw) { cand[i] = a1; cand[ixj] = a0; }
        }
      }
      __syncthreads();
    }
  }

  // ---- decode top-6000 boxes to global ----
  const float imh = iminfo[b*3+0], imw = iminfo[b*3+1];
  float4* bg = boxes_g + (size_t)b * PRE;
  for (int s = tid; s < PRE; s += 1024) {
    unsigned long long k = cand[s];
    unsigned int idx = ~(unsigned int)(k & 0xFFFFFFFFull);
    float4 bx = make_float4(0.f, 0.f, 0.f, 0.f);
    if (idx < NANCH) bx = decode_box(pred, anchors, b, (int)idx, imw, imh);
    bg[s] = bx;
  }
  // ---- live mask words to global ----
  const unsigned int liveThr = f2sort(-5.0e8f);
  for (int w = tid; w < NWORD; w += 1024) {
    unsigned int m = 0u;
    for (int k2 = 0; k2 < 32; ++k2) {
      int s = w * 32 + k2;
      if (s < PRE && (unsigned int)(cand[s] >> 32) > liveThr) m |= (1u << k2);
    }
    live_g[b * NWORD + w] = m;
  }
}

// K3: one 512-thread block per batch; register-only live state; shfl-min
// find-first; branchless VALU-only suppression sweep; ONE barrier per pick.
__global__ __launch_bounds__(NT, 1) void k_nms(
    const float4* __restrict__ boxes_g,
    const unsigned int* __restrict__ live_g,
    float* __restrict__ out) {
  __shared__ float4 bxs[PRE];          // 96000B (pick broadcast)
  __shared__ float4 obuf[POST];
  __shared__ int wpart[2][NT/64];      // per-wave find-first partials, dbuf
  const int b = blockIdx.x;
  const int tid = threadIdx.x;
  const int wave = tid >> 6, lane = tid & 63;
  const float4* bg = boxes_g + (size_t)b * PRE;
  for (int i = tid; i < PRE; i += NT) bxs[i] = bg[i];
  __syncthreads();

  // register-resident boxes: thread owns c = k*NT + tid
  float rx1[KPT], ry1[KPT], rx2[KPT], ry2[KPT];
  unsigned int alive = 0u;
  #pragma unroll
  for (int k = 0; k < KPT; ++k) {
    int c = k * NT + tid;
    float4 bb = (c < PRE) ? bxs[c] : make_float4(0.f, 0.f, 0.f, 0.f);
    rx1[k] = bb.x; ry1[k] = bb.y; rx2[k] = bb.z; ry2[k] = bb.w;
    unsigned int lv = (c < PRE) ? ((live_g[b * NWORD + (c >> 5)] >> (c & 31)) & 1u) : 0u;
    alive |= lv << k;
  }

  int it = 0;
  for (; it < POST; ++it) {
    // ---- find-first: per-thread min alive index -> wave shfl-min -> LDS ----
    int cmin = alive ? ((__ffs(alive) - 1) * NT + tid) : BIGI;
    #pragma unroll
    for (int d = 32; d > 0; d >>= 1)
      cmin = min(cmin, __shfl_xor(cmin, d));
    if (lane == 0) wpart[it & 1][wave] = cmin;
    __syncthreads();
    int j = wpart[it & 1][0];
    #pragma unroll
    for (int w = 1; w < NT/64; ++w) j = min(j, wpart[it & 1][w]);
    if (j == BIGI) break;
    float4 bj = bxs[j];  // LDS broadcast
    float areaJ = (bj.z - bj.x + 1.0f) * (bj.w - bj.y + 1.0f);
    if (tid == 0) obuf[it] = bj;
    // ---- branchless register-only suppression sweep ----
    #pragma unroll
    for (int k = 0; k < KPT; ++k) {
      float xx1 = fmaxf(bj.x, rx1[k]);
      float yy1 = fmaxf(bj.y, ry1[k]);
      float xx2 = fminf(bj.z, rx2[k]);
      float yy2 = fminf(bj.w, ry2[k]);
      float inter = fmaxf(xx2 - xx1 + 1.0f, 0.0f) * fmaxf(yy2 - yy1 + 1.0f, 0.0f);
      float areaK = (rx2[k] - rx1[k] + 1.0f) * (ry2[k] - ry1[k] + 1.0f);
      float iou = inter / (areaJ + areaK - inter);
      alive &= ~(((unsigned int)(iou > NMS_T)) << k);
    }
  }
  // ---- fill remaining picks with zeros ----
  for (int k = it + tid; k < POST; k += NT) obuf[k] = make_float4(0.f, 0.f, 0.f, 0.f);
  __syncthreads();
  // ---- coalesced output write: [b][POST][5] = (b, x1, y1, x2, y2) ----
  float* ob = out + (size_t)b * POST * 5;
  for (int i = tid; i < POST * 5; i += NT) {
    int row = i / 5, col = i - row * 5;
    float v;
    if (col == 0) v = (float)b;
    else {
      float4 bb = obuf[row];
      v = (col == 1) ? bb.x : (col == 2) ? bb.y : (col == 3) ? bb.z : bb.w;
    }
    ob[i] = v;
  }
}

extern "C" void kernel_launch(void* const* d_in, const int* in_sizes, int n_in,
                              void* d_out, int out_size, void* d_ws, size_t ws_size,
                              hipStream_t stream) {
  const float* cls     = (const float*)d_in[0];
  const float* pred    = (const float*)d_in[1];
  const float* iminfo  = (const float*)d_in[2];
  const float* anchors = (const float*)d_in[3];
  float* out = (float*)d_out;

  unsigned char* ws = (unsigned char*)d_ws;
  unsigned long long* keys = (unsigned long long*)ws;                 // 23,040,000 B
  float4* boxes_g = (float4*)(ws + (size_t)NB * NANCH * 8);           //  3,072,000 B
  unsigned int* live_g = (unsigned int*)(ws + (size_t)NB * NANCH * 8
                                            + (size_t)NB * PRE * 16); //     24,064 B

  int total = NB * NANCH;
  int blocks = (total + 255) / 256;
  k_decode<<<blocks, 256, 0, stream>>>(cls, pred, iminfo, anchors, keys);
  k_select<<<NB, 1024, 0, stream>>>(keys, pred, iminfo, anchors, boxes_g, live_g);
  k_nms<<<NB, NT, 0, stream>>>(boxes_g, live_g, out);
}

// Round 5
// 642.939 us; speedup vs baseline: 7.5566x; 1.0710x over previous
//
#include <hip/hip_runtime.h>

#define NB 32
#define NA 9
#define FH 100
#define FW 100
#define HWSZ (FH*FW)          // 10000
#define NANCH (HWSZ*NA)       // 90000
#define PRE 6000
#define POST 300
#define SORTN 8192
#define NWORD 188             // ceil(6000/32)
#define NEGV -1000000000.0f
#define NMS_T 0.7f
#define NT 512                // k_nms threads
#define KPT 12                // boxes per thread: 512*12 = 6144 >= 6000 (contiguous)
#define BIGI 0x7FFFFFFF

__device__ __forceinline__ unsigned int f2sort(float f) {
  unsigned int u = __float_as_uint(f);
  return (u & 0x80000000u) ? ~u : (u | 0x80000000u);
}

// Decode one anchor's clipped box. i in [0, NANCH): i = (h*FW + w)*NA + a
__device__ __forceinline__ float4 decode_box(const float* __restrict__ pred,
                                             const float* __restrict__ anchors,
                                             int b, int i, float imw, float imh) {
  int hw = i / NA; int a = i - hw * NA;
  int h = hw / FW; int w = hw - h * FW;
  float sx = (float)(w * 16);
  float sy = (float)(h * 16);
  float ax1 = anchors[a*4+0] + sx, ay1 = anchors[a*4+1] + sy;
  float ax2 = anchors[a*4+2] + sx, ay2 = anchors[a*4+3] + sy;
  float wa = ax2 - ax1 + 1.0f, ha = ay2 - ay1 + 1.0f;
  float cxa = ax1 + 0.5f*(wa - 1.0f), cya = ay1 + 0.5f*(ha - 1.0f);
  size_t base = (((size_t)b*36 + a*4)*FH + h)*FW + w;
  float dx = pred[base];
  float dy = pred[base + HWSZ];
  float dw = pred[base + 2*HWSZ];
  float dh = pred[base + 3*HWSZ];
  float cx = dx*wa + cxa, cy = dy*ha + cya;
  float pw = expf(dw)*wa, ph = expf(dh)*ha;
  float x1 = fminf(fmaxf(cx - 0.5f*(pw - 1.0f), 0.0f), imw - 1.0f);
  float y1 = fminf(fmaxf(cy - 0.5f*(ph - 1.0f), 0.0f), imh - 1.0f);
  float x2 = fminf(fmaxf(cx + 0.5f*(pw - 1.0f), 0.0f), imw - 1.0f);
  float y2 = fminf(fmaxf(cy + 0.5f*(ph - 1.0f), 0.0f), imh - 1.0f);
  return make_float4(x1, y1, x2, y2);
}

// K1: per-anchor score with min-size filter -> sortable key
__global__ void k_decode(const float* __restrict__ cls,
                         const float* __restrict__ pred,
                         const float* __restrict__ iminfo,
                         const float* __restrict__ anchors,
                         unsigned long long* __restrict__ keys) {
  int gid = blockIdx.x * blockDim.x + threadIdx.x;
  if (gid >= NB * NANCH) return;
  int b = gid / NANCH;
  int i = gid - b * NANCH;
  int hw = i / NA; int a = i - hw * NA;
  int h = hw / FW; int w = hw - h * FW;
  float score = cls[(((size_t)b*18 + 9 + a)*FH + h)*FW + w];
  float imh = iminfo[b*3+0], imw = iminfo[b*3+1], sc = iminfo[b*3+2];
  float4 bx = decode_box(pred, anchors, b, i, imw, imh);
  float msz = 16.0f * sc;
  bool keep = ((bx.z - bx.x + 1.0f) >= msz) && ((bx.w - bx.y + 1.0f) >= msz);
  float sf = keep ? score : NEGV;
  unsigned long long key = ((unsigned long long)f2sort(sf) << 32)
                         | (unsigned int)(~(unsigned int)i);
  keys[(size_t)b * NANCH + i] = key;
}

// K2: per-batch block: radix-threshold select -> compact -> bitonic sort ->
// decode top-6000 boxes + live mask to GLOBAL
#define SMEM_BYTES (65536 + 16384 + 16384 + 64)
__global__ __launch_bounds__(1024, 1) void k_select(
    const unsigned long long* __restrict__ keys,
    const float* __restrict__ pred,
    const float* __restrict__ iminfo,
    const float* __restrict__ anchors,
    float4* __restrict__ boxes_g,
    unsigned int* __restrict__ live_g) {
  __shared__ __align__(16) unsigned char smemRaw[SMEM_BYTES];
  unsigned long long* cand = (unsigned long long*)smemRaw;            // [8192] 65536B
  unsigned int* histA = (unsigned int*)(smemRaw + 65536);             // [4096]
  unsigned int* histB = (unsigned int*)(smemRaw + 81920);             // [4096]
  int* scal = (int*)(smemRaw + 98304);                                // [16]

  const int b = blockIdx.x;
  const int tid = threadIdx.x;
  const unsigned long long* kb = keys + (size_t)b * NANCH;

  // ---- level-1 histogram: sortable bits [31:20] ----
  for (int i = tid; i < 4096; i += 1024) histA[i] = 0;
  __syncthreads();
  for (int i = tid; i < NANCH; i += 1024)
    atomicAdd(&histA[(unsigned int)(kb[i] >> 52)], 1u);
  __syncthreads();
  {
    unsigned int *src = histA, *dst = histB;
    for (int d = 1; d < 4096; d <<= 1) {
      for (int i = tid; i < 4096; i += 1024) {
        unsigned int v = src[i];
        if (i + d < 4096) v += src[i + d];
        dst[i] = v;
      }
      __syncthreads();
      unsigned int* t = src; src = dst; dst = t;
    }
    for (int i = tid; i < 4096; i += 1024) {
      unsigned int s = src[i];
      unsigned int sn = (i < 4095) ? src[i + 1] : 0u;
      if (s >= PRE && sn < PRE) { scal[1] = i; scal[2] = (int)sn; }
    }
    __syncthreads();
  }
  const int cb = scal[1];
  const unsigned int nG = (unsigned int)scal[2];
  __syncthreads();

  // ---- level-2 histogram: within coarse bin, sortable bits [19:8] ----
  for (int i = tid; i < 4096; i += 1024) histA[i] = 0;
  __syncthreads();
  for (int i = tid; i < NANCH; i += 1024) {
    unsigned long long k = kb[i];
    if ((int)(k >> 52) == cb)
      atomicAdd(&histA[(unsigned int)((k >> 40) & 0xFFFull)], 1u);
  }
  __syncthreads();
  {
    unsigned int *src = histA, *dst = histB;
    for (int d = 1; d < 4096; d <<= 1) {
      for (int i = tid; i < 4096; i += 1024) {
        unsigned int v = src[i];
        if (i + d < 4096) v += src[i + d];
        dst[i] = v;
      }
      __syncthreads();
      unsigned int* t = src; src = dst; dst = t;
    }
    unsigned int need2 = PRE - nG;
    for (int i = tid; i < 4096; i += 1024) {
      unsigned int s = src[i];
      unsigned int sn = (i < 4095) ? src[i + 1] : 0u;
      if (s >= need2 && sn < need2) scal[3] = i;
    }
    __syncthreads();
  }
  const unsigned int thrT = ((unsigned int)cb << 20) | ((unsigned int)scal[3] << 8);

  // ---- compaction of keys with sortable >= thrT ----
  if (tid == 0) scal[0] = 0;
  __syncthreads();
  for (int i = tid; i < NANCH; i += 1024) {
    unsigned long long k = kb[i];
    if ((unsigned int)(k >> 32) >= thrT) {
      int p = atomicAdd(&scal[0], 1);
      if (p < SORTN) cand[p] = k;
    }
  }
  __syncthreads();
  {
    int cnt = scal[0]; if (cnt > SORTN) cnt = SORTN;
    for (int i = tid; i < SORTN; i += 1024)
      if (i >= cnt) cand[i] = 0ull;
  }
  __syncthreads();

  // ---- bitonic sort, descending ----
  for (int k = 2; k <= SORTN; k <<= 1) {
    for (int j = k >> 1; j > 0; j >>= 1) {
      for (int i = tid; i < SORTN; i += 1024) {
        int ixj = i ^ j;
        if (ixj > i) {
          unsigned long long a0 = cand[i], a1 = cand[ixj];
          bool up = (i & k) != 0;
          bool sw = up ? (a0 > a1) : (a0 < a1);
          if (sw) { cand[i] = a1; cand[ixj] = a0; }
        }
      }
      __syncthreads();
    }
  }

  // ---- decode top-6000 boxes to global ----
  const float imh = iminfo[b*3+0], imw = iminfo[b*3+1];
  float4* bg = boxes_g + (size_t)b * PRE;
  for (int s = tid; s < PRE; s += 1024) {
    unsigned long long k = cand[s];
    unsigned int idx = ~(unsigned int)(k & 0xFFFFFFFFull);
    float4 bx = make_float4(0.f, 0.f, 0.f, 0.f);
    if (idx < NANCH) bx = decode_box(pred, anchors, b, (int)idx, imw, imh);
    bg[s] = bx;
  }
  // ---- live mask words to global ----
  const unsigned int liveThr = f2sort(-5.0e8f);
  for (int w = tid; w < NWORD; w += 1024) {
    unsigned int m = 0u;
    for (int k2 = 0; k2 < 32; ++k2) {
      int s = w * 32 + k2;
      if (s < PRE && (unsigned int)(cand[s] >> 32) > liveThr) m |= (1u << k2);
    }
    live_g[b * NWORD + w] = m;
  }
}

// K3: one 512-thread block per batch; CONTIGUOUS register-resident ownership;
// ballot+readlane find-first (no shfl chains); one barrier per pick.
__global__ __launch_bounds__(NT, 1) void k_nms(
    const float4* __restrict__ boxes_g,
    const unsigned int* __restrict__ live_g,
    float* __restrict__ out) {
  __shared__ float4 bxs[PRE];          // 96000B (pick broadcast)
  __shared__ float4 obuf[POST];
  __shared__ int wpart[2][NT/64];      // per-wave find-first partials, dbuf
  const int b = blockIdx.x;
  const int tid = threadIdx.x;
  const int wave = tid >> 6, lane = tid & 63;
  const float4* bg = boxes_g + (size_t)b * PRE;
  for (int i = tid; i < PRE; i += NT) bxs[i] = bg[i];
  __syncthreads();

  // contiguous ownership: thread owns c = tid*KPT + k, k = 0..KPT-1
  float rx1[KPT], ry1[KPT], rx2[KPT], ry2[KPT];
  unsigned int alive = 0u;
  #pragma unroll
  for (int k = 0; k < KPT; ++k) {
    int c = tid * KPT + k;
    float4 bb = (c < PRE) ? bxs[c] : make_float4(0.f, 0.f, 0.f, 0.f);
    rx1[k] = bb.x; ry1[k] = bb.y; rx2[k] = bb.z; ry2[k] = bb.w;
    unsigned int lv = (c < PRE) ? ((live_g[b * NWORD + (c >> 5)] >> (c & 31)) & 1u) : 0u;
    alive |= lv << k;
  }

  int it = 0;
  for (; it < POST; ++it) {
    // ---- find-first: ballot -> readlane (wave), LDS combine (block) ----
    int cmin = tid * KPT + (__ffs(alive) - 1);       // valid only if alive!=0
    unsigned long long bal = __ballot(alive != 0u);
    int wmin = BIGI;
    if (bal) {                                       // wave-uniform branch
      int fl = __ffsll(bal) - 1;
      wmin = __builtin_amdgcn_readlane(cmin, fl);
    }
    if (lane == 0) wpart[it & 1][wave] = wmin;
    __syncthreads();
    int j = wpart[it & 1][0];
    #pragma unroll
    for (int w = 1; w < NT/64; ++w) j = min(j, wpart[it & 1][w]);
    if (j == BIGI) break;
    float4 bj = bxs[j];  // LDS broadcast
    float areaJ = (bj.z - bj.x + 1.0f) * (bj.w - bj.y + 1.0f);
    if (tid == 0) obuf[it] = bj;
    // ---- register-only suppression sweep (self-suppresses pick via IoU=1) ----
    if (alive) {
      #pragma unroll
      for (int k = 0; k < KPT; ++k) {
        float xx1 = fmaxf(bj.x, rx1[k]);
        float yy1 = fmaxf(bj.y, ry1[k]);
        float xx2 = fminf(bj.z, rx2[k]);
        float yy2 = fminf(bj.w, ry2[k]);
        float inter = fmaxf(xx2 - xx1 + 1.0f, 0.0f) * fmaxf(yy2 - yy1 + 1.0f, 0.0f);
        float areaK = (rx2[k] - rx1[k] + 1.0f) * (ry2[k] - ry1[k] + 1.0f);
        float iou = inter / (areaJ + areaK - inter);
        alive &= ~(((unsigned int)(iou > NMS_T)) << k);
      }
    }
  }
  // ---- fill remaining picks with zeros ----
  for (int k = it + tid; k < POST; k += NT) obuf[k] = make_float4(0.f, 0.f, 0.f, 0.f);
  __syncthreads();
  // ---- coalesced output write: [b][POST][5] = (b, x1, y1, x2, y2) ----
  float* ob = out + (size_t)b * POST * 5;
  for (int i = tid; i < POST * 5; i += NT) {
    int row = i / 5, col = i - row * 5;
    float v;
    if (col == 0) v = (float)b;
    else {
      float4 bb = obuf[row];
      v = (col == 1) ? bb.x : (col == 2) ? bb.y : (col == 3) ? bb.z : bb.w;
    }
    ob[i] = v;
  }
}

extern "C" void kernel_launch(void* const* d_in, const int* in_sizes, int n_in,
                              void* d_out, int out_size, void* d_ws, size_t ws_size,
                              hipStream_t stream) {
  const float* cls     = (const float*)d_in[0];
  const float* pred    = (const float*)d_in[1];
  const float* iminfo  = (const float*)d_in[2];
  const float* anchors = (const float*)d_in[3];
  float* out = (float*)d_out;

  unsigned char* ws = (unsigned char*)d_ws;
  unsigned long long* keys = (unsigned long long*)ws;                 // 23,040,000 B
  float4* boxes_g = (float4*)(ws + (size_t)NB * NANCH * 8);           //  3,072,000 B
  unsigned int* live_g = (unsigned int*)(ws + (size_t)NB * NANCH * 8
                                            + (size_t)NB * PRE * 16); //     24,064 B

  int total = NB * NANCH;
  int blocks = (total + 255) / 256;
  k_decode<<<blocks, 256, 0, stream>>>(cls, pred, iminfo, anchors, keys);
  k_select<<<NB, 1024, 0, stream>>>(keys, pred, iminfo, anchors, boxes_g, live_g);
  k_nms<<<NB, NT, 0, stream>>>(boxes_g, live_g, out);
}